// Round 7
// baseline (264.666 us; speedup 1.0000x reference)
//
#include <hip/hip_runtime.h>
#include <math.h>

#define NB 16
#define NPG 1024
#define DIN 16
#define ED 8
#define NHEADS 5
#define OUT1 6
#define HID 30
#define C1 32
#define C2 4
#define NN (NB*NPG)      // 16384 nodes
#define EE (NN*32)       // 524288 edges
#define EPG 32768        // edges per graph (graph-contiguous in edge_index)
#define CH 16            // chunks per graph
#define CE 2048          // edges per chunk
#define ZTOT (NB*C1*HID + 2*NB*C1*C1)   // 48128 floats: x2+adj2+Gm zero region

__device__ __forceinline__ float lrelu(float v){ return v >= 0.f ? v : 0.2f*v; }

// chunk mapping for 256-block edge kernels: XCD-affine, block -> (g, c)
// NOTE: all 16 chunk-blocks of graph g share blockIdx%8 == g&7 -> same XCD/L2,
// which makes the last-block-scans protocol in k_hist_chunk an intra-L2 handoff.
__device__ __forceinline__ void chunk_gc(int& g, int& c){
    int x = blockIdx.x & 7;
    int j = blockIdx.x >> 3;     // 0..31
    g = x + 8*(j >> 4);          // 2 graphs per XCD
    c = j & 15;
}

// XCD-affinity mapping for 2048-block edge kernels
__device__ __forceinline__ size_t xcd_chunk_base(){
    int x = blockIdx.x & 7;
    int j = blockIdx.x >> 3;            // 0..255 position within this XCD
    int g = x + 8*(j >> 7);             // 2 graphs per XCD
    int c = j & 127;                    // 128 chunks per graph
    return (size_t)g*EPG + (size_t)c*256;
}

// ---------- merged: per-chunk dual LDS histograms + INLINE per-graph cumscan
//            (k_cumscan folded via last-block-per-graph) + zero-init of x2/adj2/Gm
//            (big memset folded) + node projection (blocks 256..319) ----------
__global__ void k_hist_chunk(const int* __restrict__ src, const int* __restrict__ dst,
                             int* __restrict__ histD, int* __restrict__ histS,
                             const float* __restrict__ x, const float* __restrict__ W1,
                             const float* __restrict__ as1, const float* __restrict__ ad1,
                             float* __restrict__ h1, float* __restrict__ hs1, float* __restrict__ hd1,
                             int* __restrict__ rowptr, int* __restrict__ rowptrS,
                             unsigned int* __restrict__ hctr, float* __restrict__ zbase){
    int t = threadIdx.x;
    if (blockIdx.x < 256){
        __shared__ int hD[NPG], hS[NPG];
        __shared__ int wtot[4], wbase[4];
        __shared__ unsigned int lastsh;
        // folded zero-init: x2/adj2/Gm region (consumed by k_Tp's atomics, 4 dispatches later)
        {
            int i = blockIdx.x*256 + t;
            if (i < ZTOT) zbase[i] = 0.f;
        }
        for (int i = t; i < NPG; i += 256){ hD[i] = 0; hS[i] = 0; }
        __syncthreads();
        int g, c; chunk_gc(g, c);
        size_t e0 = ((size_t)g*CH + c)*CE;
        #pragma unroll
        for (int i = 0; i < 8; i++){
            size_t e = e0 + i*256 + t;
            atomicAdd(&hD[dst[e] & (NPG-1)], 1);
            atomicAdd(&hS[src[e] & (NPG-1)], 1);
        }
        __syncthreads();
        size_t hb = ((size_t)g*CH + c)*NPG;
        for (int i = t; i < NPG; i += 256){
            histD[hb + i] = hD[i];
            histS[hb + i] = hS[i];
        }
        // ---- completion protocol (threadFenceReduction pattern): last chunk-block
        //      of graph g performs the cumscan inline. Hist lines are same-XCD L2. ----
        __syncthreads();
        if (t == 0){
            __threadfence();
            lastsh = atomicAdd(&hctr[g], 1u);
        }
        __syncthreads();
        if (lastsh != CH-1) return;
        if (t == 0) __threadfence();   // acquire side
        __syncthreads();
        // ---- inline cumscan for graph g (D then S): 256 threads x 4 nodes each.
        //      Identical arithmetic to the old k_cumscan (bit-identical rowptr). ----
        for (int pass = 0; pass < 2; pass++){
            int* hist = (pass == 0) ? histD : histS;
            int* rp   = (pass == 0) ? rowptr : rowptrS;
            int n0 = 4*t;
            int runs[4];
            #pragma unroll
            for (int i = 0; i < 4; i++){
                int n = n0 + i;
                int run = 0;
                #pragma unroll
                for (int cc = 0; cc < CH; cc++){
                    size_t idx = ((size_t)g*CH + cc)*NPG + n;
                    int v = hist[idx];
                    hist[idx] = run;     // exclusive per-chunk prefix (in place)
                    run += v;
                }
                runs[i] = run;
            }
            int tsum = runs[0] + runs[1] + runs[2] + runs[3];
            int lane = t & 63, wv = t >> 6;
            int sincl = tsum;
            #pragma unroll
            for (int off = 1; off < 64; off <<= 1){
                int v = __shfl_up(sincl, off, 64);
                if (lane >= off) sincl += v;
            }
            if (lane == 63) wtot[wv] = sincl;
            __syncthreads();
            if (t == 0){
                int r = 0;
                #pragma unroll
                for (int w = 0; w < 4; w++){ wbase[w] = r; r += wtot[w]; }
            }
            __syncthreads();
            int e = wbase[wv] + sincl - tsum;   // exclusive node-prefix for node n0
            #pragma unroll
            for (int i = 0; i < 4; i++){
                rp[g*NPG + n0 + i] = g*EPG + e;
                e += runs[i];
            }
            if (g == NB-1 && t == 255) rp[NN] = EE;
            __syncthreads();   // protect wtot/wbase reuse across passes
        }
        return;
    }
    // node projection part (blocks 256..319)
    __shared__ float Ws[DIN*HID];
    __shared__ float as_s[HID], ad_s[HID];
    for (int i = t; i < DIN*HID; i += blockDim.x) Ws[i] = W1[i];
    if (t < HID){ as_s[t] = as1[t]; ad_s[t] = ad1[t]; }
    __syncthreads();
    int n = (blockIdx.x - 256)*blockDim.x + t;
    if (n >= NN) return;
    float xv[DIN];
    #pragma unroll
    for (int i = 0; i < DIN; i++) xv[i] = x[n*DIN + i];
    float hv[HID];
    #pragma unroll
    for (int j = 0; j < HID; j++){
        float a = 0.f;
        #pragma unroll
        for (int i = 0; i < DIN; i++) a += xv[i]*Ws[i*HID + j];
        hv[j] = a; h1[(size_t)n*HID + j] = a;
    }
    #pragma unroll
    for (int h = 0; h < NHEADS; h++){
        float s = 0.f, d = 0.f;
        #pragma unroll
        for (int c2 = 0; c2 < OUT1; c2++){ s += hv[h*OUT1+c2]*as_s[h*OUT1+c2]; d += hv[h*OUT1+c2]*ad_s[h*OUT1+c2]; }
        hs1[n*NHEADS + h] = s; hd1[n*NHEADS + h] = d;
    }
}

// ---------- deterministic scatter: slot = rowptr + chunk-base + LDS rank (no global atomics) ----------
__global__ void k_scatter_det(const int* __restrict__ src, const int* __restrict__ dst,
                              const int* __restrict__ rowptr, const int* __restrict__ rowptrS,
                              const int* __restrict__ histD, const int* __restrict__ histS,
                              int* __restrict__ srcs, int* __restrict__ eid,
                              int* __restrict__ dsts, int* __restrict__ nbrS){
    __shared__ int baseD[NPG], baseS[NPG];
    int t = threadIdx.x;
    int g, c; chunk_gc(g, c);
    size_t hb = ((size_t)g*CH + c)*NPG;
    for (int i = t; i < NPG; i += 256){
        baseD[i] = rowptr[g*NPG + i] + histD[hb + i];
        baseS[i] = rowptrS[g*NPG + i] + histS[hb + i];
    }
    __syncthreads();
    size_t e0 = ((size_t)g*CH + c)*CE;
    #pragma unroll
    for (int i = 0; i < 8; i++){
        size_t e = e0 + i*256 + t;
        int s = src[e], d = dst[e];
        int p = atomicAdd(&baseD[d & (NPG-1)], 1);
        srcs[p] = s; eid[p] = (int)e; dsts[p] = d;
        int pS = atomicAdd(&baseS[s & (NPG-1)], 1);
        nbrS[pS] = d;
    }
}

// ---------- edge proj + conv1 LOGITS into per-head planes (2048 blocks, coalesced writes) ----------
__global__ void k_elogit(const float* __restrict__ ea, const float* __restrict__ We1,
                         const float* __restrict__ Wep1,
                         const int* __restrict__ srcs, const int* __restrict__ eid,
                         const int* __restrict__ dsts,
                         const float* __restrict__ hs1, const float* __restrict__ hd1,
                         float* __restrict__ lg1T, float* __restrict__ ewp1s){
    __shared__ float W[ED*NHEADS];
    __shared__ float Wp[ED];
    int t = threadIdx.x;
    if (t < ED*NHEADS) W[t] = We1[t];
    if (t < ED) Wp[t] = Wep1[t];
    __syncthreads();
    size_t k = xcd_chunk_base() + t;
    int s = srcs[k], e = eid[k], d = dsts[k];
    float a[ED];
    #pragma unroll
    for (int i = 0; i < ED; i++) a[i] = ea[(size_t)e*ED + i];
    const float* hsr = hs1 + (size_t)s*NHEADS;
    const float* hdr = hd1 + (size_t)d*NHEADS;
    #pragma unroll
    for (int h = 0; h < NHEADS; h++){
        float sv = 0.f;
        #pragma unroll
        for (int i = 0; i < ED; i++) sv += a[i]*W[i*NHEADS + h];
        lg1T[(size_t)h*EE + k] = lrelu(hsr[h] + hdr[h] + sv);
    }
    float sv = 0.f;
    #pragma unroll
    for (int i = 0; i < ED; i++) sv += a[i]*Wp[i];
    ewp1s[k] = sv;
}

// ---------- conv1 aggregation + pool-conv1 prep + dedup (k_pd folded in) ----------
__global__ __launch_bounds__(640) void k_conv1pd(const int* __restrict__ srcs,
                            const int* __restrict__ rowptr,
                            const float* __restrict__ h1, const float* __restrict__ lg1T,
                            float* __restrict__ x1,
                            const float* __restrict__ Wp1, const float* __restrict__ asp,
                            const float* __restrict__ adp,
                            float* __restrict__ hp1, float* __restrict__ hsp,
                            float* __restrict__ hdp,
                            const int* __restrict__ rowptrS, const int* __restrict__ nbrS,
                            int* __restrict__ unbr, int* __restrict__ ucnt,
                            float* __restrict__ scal){
    __shared__ __align__(16) float smem[35968];   // 143872 B (union of both paths)
    int t = threadIdx.x;

    if (blockIdx.x < 64){
        // ---- dedup via per-thread LDS bitmap (256 active threads, 256 nodes/block) ----
        unsigned int* bm = (unsigned int*)smem;          // 256*33
        int* red = (int*)(smem + 256*33);                // 256
        if (t < 256){
            unsigned int* mybm = &bm[t*33];
            #pragma unroll
            for (int i = 0; i < 32; i++) mybm[i] = 0u;
            int n = blockIdx.x*256 + t;
            int cnt = 0;
            int k0 = rowptrS[n], k1 = rowptrS[n+1];
            for (int k = k0; k < k1; k++){
                int m = nbrS[k];
                int loc = m & (NPG-1);
                unsigned int w = (unsigned int)(loc >> 5);
                unsigned int bit = 1u << (loc & 31);
                unsigned int old = mybm[w];
                if (!(old & bit)){
                    mybm[w] = old | bit;
                    unbr[k0 + cnt] = m;
                    cnt++;
                }
            }
            ucnt[n] = cnt;
            red[t] = cnt;
        }
        __syncthreads();
        for (int s = 128; s > 0; s >>= 1){
            if (t < s) red[t] += red[t+s];
            __syncthreads();
        }
        if (t == 0) atomicAdd(&scal[0], (float)red[0]);
        return;
    }

    // ---- conv1 + proj path ----
    float* hls  = smem;            // NPG*HID = 30720 floats (122880 B)
    float* x1s  = smem + 30720;    // 64*33 = 2112 (padded rows)
    float* hp1s = smem + 32832;    // 64*33 = 2112 (padded rows)
    float* Wp1s = smem + 34944;    // 960
    float* as_s = smem + 35904;    // 32
    float* ad_s = smem + 35936;    // 32

    int blk = blockIdx.x - 64;     // 64 is a multiple of 8 -> XCD mapping preserved
    int xx = blk & 7;
    int j = blk >> 3;              // 0..31
    int g = xx + 8*(j >> 4);       // 2 graphs per XCD
    int seg = j & 15;              // 64-node segment
    const float4* hg4 = (const float4*)(h1 + (size_t)g*NPG*HID);
    float4* hls4 = (float4*)hls;
    for (int i = t; i < NPG*HID/4; i += 640) hls4[i] = hg4[i];
    for (int i = t; i < HID*C1; i += 640) Wp1s[i] = Wp1[i];
    if (t < C1){ as_s[t] = asp[t]; ad_s[t] = adp[t]; }
    __syncthreads();

    int nlo = t/10;
    int nl = seg*64 + nlo;
    int r = t - nlo*10;
    int h = r >> 1;
    int q = r & 1;
    int n = g*NPG + nl;
    int k0 = rowptr[n], k1 = rowptr[n+1];
    const float* lgh = lg1T + (size_t)h*EE;
    int off = h*OUT1 + q*3;
    float m = -INFINITY, den = 0.f;
    float acc[3] = {0.f, 0.f, 0.f};
    int k = k0;
    for (; k + 4 <= k1; k += 4){
        float l0 = lgh[k+0], l1 = lgh[k+1], l2 = lgh[k+2], l3 = lgh[k+3];
        int s0 = srcs[k+0] & (NPG-1), s1 = srcs[k+1] & (NPG-1);
        int s2 = srcs[k+2] & (NPG-1), s3 = srcs[k+3] & (NPG-1);
        const float* p0 = hls + s0*HID + off;
        const float* p1 = hls + s1*HID + off;
        const float* p2 = hls + s2*HID + off;
        const float* p3 = hls + s3*HID + off;
        float mb = fmaxf(fmaxf(l0, l1), fmaxf(l2, l3));
        float mn = fmaxf(m, mb);
        float f  = expf(m - mn);       // first batch: exp(-inf)=0
        float e0 = expf(l0 - mn), e1 = expf(l1 - mn);
        float e2 = expf(l2 - mn), e3 = expf(l3 - mn);
        m = mn;
        den = den*f + e0 + e1 + e2 + e3;
        #pragma unroll
        for (int c = 0; c < 3; c++)
            acc[c] = acc[c]*f + e0*p0[c] + e1*p1[c] + e2*p2[c] + e3*p3[c];
    }
    for (; k < k1; k++){
        float l = lgh[k];
        int s = srcs[k] & (NPG-1);
        float mn = fmaxf(m, l);
        float f  = expf(m - mn);
        float ex = expf(l - mn);
        m = mn;
        den = den*f + ex;
        const float* hr = hls + s*HID + off;
        #pragma unroll
        for (int c = 0; c < 3; c++) acc[c] = acc[c]*f + ex*hr[c];
    }
    float inv = 1.f / (den + 1e-16f);
    #pragma unroll
    for (int c = 0; c < 3; c++){
        float v = acc[c]*inv;
        x1[(size_t)n*HID + off + c] = v;
        x1s[nlo*33 + off + c] = v;
    }
    __syncthreads();

    // proj tail: hp1 tile = x1_tile @ Wp1 (identical FMA order to old k_pd)
    int nbase = g*NPG + seg*64;
    for (int o = t; o < 64*C1; o += 640){
        int nn = o >> 5, c = o & 31;
        float a = 0.f;
        #pragma unroll
        for (int d = 0; d < HID; d++) a += x1s[nn*33 + d]*Wp1s[d*C1 + c];
        hp1s[nn*33 + c] = a;
        hp1[(size_t)(nbase + nn)*C1 + c] = a;
    }
    __syncthreads();
    if (t < 64){
        float s = 0.f, dd = 0.f;
        #pragma unroll
        for (int c = 0; c < C1; c++){
            float a = hp1s[t*33 + c];
            s += a*as_s[c]; dd += a*ad_s[c];
        }
        hsp[nbase + t] = s; hdp[nbase + t] = dd;
    }
}

// ---------- pool-conv1 aggregation: graph-local hp1+hsp staged in LDS (float4), inline logits,
//            fused cluster softmax. 256 blocks (16/graph) x 512 threads. ----------
__global__ __launch_bounds__(512) void k_pool1_agg(const int* __restrict__ srcs,
                            const int* __restrict__ rowptr,
                            const float* __restrict__ hp1, const float* __restrict__ hsp,
                            const float* __restrict__ hdp, const float* __restrict__ ewp1s,
                            float* __restrict__ ssoft){
    __shared__ float hls[NPG*33];   // 135168 B, padded rows -> banks rotate
    __shared__ float sm[64*33];     // 8448 B
    __shared__ __align__(16) float hsps[NPG];   // 4096 B
    __shared__ float hdps[64];      // 256 B
    int t = threadIdx.x;
    int xx = blockIdx.x & 7;
    int j = blockIdx.x >> 3;
    int g = xx + 8*(j >> 4);
    int seg = j & 15;
    const float4* hg4 = (const float4*)(hp1 + (size_t)g*NPG*C1);
    for (int i = t; i < NPG*C1/4; i += 512){
        float4 v = hg4[i];
        int s = i >> 3, c = (i & 7)*4;
        float* p = &hls[s*33 + c];
        p[0] = v.x; p[1] = v.y; p[2] = v.z; p[3] = v.w;
    }
    {
        const float4* hs4 = (const float4*)(hsp + (size_t)g*NPG);
        float4* hsps4 = (float4*)hsps;
        for (int i = t; i < NPG/4; i += 512) hsps4[i] = hs4[i];
    }
    if (t < 64) hdps[t] = hdp[g*NPG + seg*64 + t];
    __syncthreads();
    int nl = t >> 3, q = t & 7;
    int n = g*NPG + seg*64 + nl;
    int k0 = rowptr[n], k1 = rowptr[n+1];
    float hdv = hdps[nl];
    float m = -INFINITY, den = 0.f;
    float acc[4] = {0.f, 0.f, 0.f, 0.f};
    int k = k0;
    for (; k + 4 <= k1; k += 4){
        int sl0 = srcs[k+0] & (NPG-1), sl1 = srcs[k+1] & (NPG-1);
        int sl2 = srcs[k+2] & (NPG-1), sl3 = srcs[k+3] & (NPG-1);
        float l0 = lrelu(hsps[sl0] + hdv + ewp1s[k+0]);
        float l1 = lrelu(hsps[sl1] + hdv + ewp1s[k+1]);
        float l2 = lrelu(hsps[sl2] + hdv + ewp1s[k+2]);
        float l3 = lrelu(hsps[sl3] + hdv + ewp1s[k+3]);
        int b0 = sl0*33 + q*4, b1 = sl1*33 + q*4;
        int b2 = sl2*33 + q*4, b3 = sl3*33 + q*4;
        float mb = fmaxf(fmaxf(l0, l1), fmaxf(l2, l3));
        float mn = fmaxf(m, mb);
        float f  = expf(m - mn);
        float e0 = expf(l0 - mn), e1 = expf(l1 - mn);
        float e2 = expf(l2 - mn), e3 = expf(l3 - mn);
        m = mn;
        den = den*f + e0 + e1 + e2 + e3;
        #pragma unroll
        for (int c = 0; c < 4; c++)
            acc[c] = acc[c]*f + e0*hls[b0+c] + e1*hls[b1+c] + e2*hls[b2+c] + e3*hls[b3+c];
    }
    for (; k < k1; k++){
        int sl = srcs[k] & (NPG-1);
        float l = lrelu(hsps[sl] + hdv + ewp1s[k]);
        int b = sl*33 + q*4;
        float mn = fmaxf(m, l);
        float f  = expf(m - mn);
        float ex = expf(l - mn);
        m = mn;
        den = den*f + ex;
        #pragma unroll
        for (int c = 0; c < 4; c++) acc[c] = acc[c]*f + ex*hls[b+c];
    }
    float inv = 1.f / (den + 1e-16f);
    #pragma unroll
    for (int c = 0; c < 4; c++) sm[nl*33 + q*4 + c] = acc[c]*inv;
    __syncthreads();
    // cluster softmax over the node's 32 channels (redundant per slice-thread)
    float mx = -INFINITY;
    #pragma unroll 8
    for (int i = 0; i < C1; i++) mx = fmaxf(mx, sm[nl*33 + i]);
    float sum = 0.f;
    #pragma unroll 8
    for (int i = 0; i < C1; i++) sum += expf(sm[nl*33 + i] - mx);
    float is = 1.f/sum;
    #pragma unroll
    for (int c = 0; c < 4; c++)
        ssoft[(size_t)n*C1 + q*4 + c] = expf(sm[nl*33 + q*4 + c] - mx)*is;
}

// ---------- fused T + diffpool partials (k_partials folded into k_T) ----------
__global__ __launch_bounds__(512) void k_Tp(const int* __restrict__ rowptrS,
                    const int* __restrict__ unbr,
                    const int* __restrict__ ucnt, const float* __restrict__ ssoft,
                    const float* __restrict__ x1,
                    float* __restrict__ adj2, float* __restrict__ Gm,
                    float* __restrict__ x2){
    __shared__ float sls[NPG*33];               // 135168 B
    __shared__ __align__(16) float tsh[64*C1];  // 8192 B
    __shared__ __align__(16) float xsh[64*HID]; // 7680 B
    int t = threadIdx.x;
    int xx = blockIdx.x & 7;
    int j = blockIdx.x >> 3;
    int g = xx + 8*(j >> 4);
    int seg = j & 15;
    const float4* sg4 = (const float4*)(ssoft + (size_t)g*NPG*C1);
    for (int i = t; i < NPG*C1/4; i += 512){
        float4 v = sg4[i];
        int s = i >> 3, c = (i & 7)*4;
        float* p = &sls[s*33 + c];
        p[0] = v.x; p[1] = v.y; p[2] = v.z; p[3] = v.w;
    }
    {
        size_t xbase = ((size_t)g*NPG + seg*64)*HID;
        const float4* x4 = (const float4*)(x1 + xbase);
        float4* xsh4 = (float4*)xsh;
        for (int i = t; i < 64*HID/4; i += 512) xsh4[i] = x4[i];
    }
    __syncthreads();
    int nl = t >> 3, q = t & 7;
    int n = g*NPG + seg*64 + nl;
    int k0 = rowptrS[n];
    int cnt = ucnt[n];
    float acc[4] = {0.f, 0.f, 0.f, 0.f};
    int i = 0;
    for (; i + 4 <= cnt; i += 4){
        int b0 = (unbr[k0+i+0] & (NPG-1))*33 + q*4;
        int b1 = (unbr[k0+i+1] & (NPG-1))*33 + q*4;
        int b2 = (unbr[k0+i+2] & (NPG-1))*33 + q*4;
        int b3 = (unbr[k0+i+3] & (NPG-1))*33 + q*4;
        #pragma unroll
        for (int c = 0; c < 4; c++)
            acc[c] += sls[b0+c] + sls[b1+c] + sls[b2+c] + sls[b3+c];
    }
    for (; i < cnt; i++){
        int b = (unbr[k0+i] & (NPG-1))*33 + q*4;
        #pragma unroll
        for (int c = 0; c < 4; c++) acc[c] += sls[b+c];
    }
    #pragma unroll
    for (int c = 0; c < 4; c++) tsh[nl*C1 + q*4 + c] = acc[c];
    __syncthreads();

    // ---- partials phase (formerly k_partials): 512 threads, 2 outputs each ----
    float accA[2] = {0.f, 0.f}, accG[2] = {0.f, 0.f}, accX[2] = {0.f, 0.f};
    int cA[2], kA[2], cX[2], dX[2];
    #pragma unroll
    for (int q2 = 0; q2 < 2; q2++){
        int p = t + q2*512;
        cA[q2] = p >> 5; kA[q2] = p & 31;
        cX[q2] = p / HID; dX[q2] = p - cX[q2]*HID;   // valid only when p < 960
    }
    const float* srow = sls + (seg*64)*33;
    for (int r = 0; r < 64; r++){
        const float* sr = srow + r*33;
        const float* tr = tsh + r*C1;
        const float* xr = xsh + r*HID;
        #pragma unroll
        for (int q2 = 0; q2 < 2; q2++){
            float sc = sr[cA[q2]];
            accA[q2] += sc*tr[kA[q2]];
            accG[q2] += sc*sr[kA[q2]];
        }
        #pragma unroll
        for (int q2 = 0; q2 < 2; q2++){
            int p = t + q2*512;
            if (p < C1*HID) accX[q2] += sr[cX[q2]]*xr[dX[q2]];
        }
    }
    int b = g;
    #pragma unroll
    for (int q2 = 0; q2 < 2; q2++){
        int p = t + q2*512;
        atomicAdd(&adj2[(size_t)b*1024 + p], accA[q2]);
        atomicAdd(&Gm[(size_t)b*1024 + p], accG[q2]);
        if (p < C1*HID) atomicAdd(&x2[((size_t)b*C1 + cX[q2])*HID + dX[q2]], accX[q2]);
    }
}

// ---------- fused tail: all weights LDS-staged in one burst ----------
__global__ __launch_bounds__(256) void k_tail(const float* __restrict__ x2, const float* __restrict__ adj2,
                       const float* __restrict__ Gm,
                       const float* __restrict__ Wp2, const float* __restrict__ asp,
                       const float* __restrict__ adp, const float* __restrict__ Wep2,
                       const float* __restrict__ Wf1, const float* __restrict__ bf1,
                       const float* __restrict__ Wf2, const float* __restrict__ bf2,
                       float* __restrict__ out, float* __restrict__ scal,
                       unsigned int* __restrict__ ctr){
    int b = blockIdx.x;
    int t = threadIdx.x;  // 256
    __shared__ float x2s[C1*HID];     // 960
    __shared__ float a2s[C1*C1];      // 1024
    __shared__ float Wps[HID*C2];     // 120
    __shared__ float Wf1s[C2*HID*32]; // 3840 (15360 B)
    __shared__ float asps[C2], adps[C2];
    __shared__ float bf1s[32], Wf2s[64], bf2s[2];
    __shared__ float wepsh;
    __shared__ float h2s[C1*C2];
    __shared__ float hs2s[C1], hd2s[C1];
    __shared__ float sss[C1*C2];      // softmax(s2)
    __shared__ float x3s[C2*HID];     // 120
    __shared__ float zsh[32];
    __shared__ float red[256], red2[256];

    // ---- one batched, coalesced load burst: everything this kernel will ever read ----
    float gv[4];
    #pragma unroll
    for (int q = 0; q < 4; q++) gv[q] = Gm[(size_t)b*1024 + t + q*256];
    for (int i = t; i < C1*HID; i += 256) x2s[i] = x2[(size_t)b*C1*HID + i];
    for (int i = t; i < C1*C1; i += 256) a2s[i] = adj2[(size_t)b*C1*C1 + i];
    for (int i = t; i < C2*HID*32; i += 256) Wf1s[i] = Wf1[i];
    if (t < HID*C2) Wps[t] = Wp2[t];
    if (t < C2){ asps[t] = asp[t]; adps[t] = adp[t]; }
    if (t < 32) bf1s[t] = bf1[t];
    if (t < 64) Wf2s[t] = Wf2[t];
    if (t < 2)  bf2s[t] = bf2[t];
    if (t == 0) wepsh = Wep2[0];
    __syncthreads();

    // ---- phase 1a (parallel over 128 threads): h2 = x2@Wp2 ----
    if (t < C1*C2){
        int i = t >> 2, c = t & 3;
        float a = 0.f;
        #pragma unroll
        for (int d = 0; d < HID; d++) a += x2s[i*HID + d]*Wps[d*C2 + c];
        h2s[t] = a;
    }
    // ---- fused reductions: trace(adj2) + ||G||_F^2 (one tree, two lanes) ----
    {
        float lfr = gv[0]*gv[0] + gv[1]*gv[1] + gv[2]*gv[2] + gv[3]*gv[3];
        float ltr = (t < C1) ? a2s[t*33] : 0.f;   // diag: t*C1+t
        red[t] = ltr; red2[t] = lfr;
        __syncthreads();
        for (int s = 128; s > 0; s >>= 1){
            if (t < s){ red[t] += red[t+s]; red2[t] += red2[t+s]; }
            __syncthreads();
        }
        if (t == 0){ atomicAdd(&scal[1], red[0]); atomicAdd(&scal[2], red2[0]); }
    }
    // ---- phase 1b: attention scalars ----
    if (t < C1){
        float s = 0.f, dd = 0.f;
        #pragma unroll
        for (int c = 0; c < C2; c++){ s += h2s[t*C2 + c]*asps[c]; dd += h2s[t*C2 + c]*adps[c]; }
        hs2s[t] = s; hd2s[t] = dd;
    }
    __syncthreads();
    // ---- phase 2: dense EGAT agg over 32 sources + softmax over C2 (all LDS) ----
    if (t < C1){
        int j = t;
        float hdv = hd2s[j];
        float wep = wepsh;
        float m = -INFINITY;
        for (int i = 0; i < C1; i++)
            m = fmaxf(m, lrelu(hs2s[i] + hdv + a2s[i*C1 + j]*wep));
        float den = 0.f;
        float acc[C2] = {0,0,0,0};
        for (int i = 0; i < C1; i++){
            float ex = expf(lrelu(hs2s[i] + hdv + a2s[i*C1 + j]*wep) - m);
            den += ex;
            #pragma unroll
            for (int c = 0; c < C2; c++) acc[c] += ex * h2s[i*C2 + c];
        }
        float inv = 1.f/(den + 1e-16f);
        float v[C2]; float mx = -INFINITY;
        #pragma unroll
        for (int c = 0; c < C2; c++){ v[c] = acc[c]*inv; mx = fmaxf(mx, v[c]); }
        float sum = 0.f;
        #pragma unroll
        for (int c = 0; c < C2; c++){ v[c] = expf(v[c] - mx); sum += v[c]; }
        float i2 = 1.f/sum;
        #pragma unroll
        for (int c = 0; c < C2; c++) sss[j*C2 + c] = v[c]*i2;
    }
    __syncthreads();
    // ---- phase 3: x3 = S^T x2 (LDS only) and reg2 ----
    if (t < C2*HID){
        int c = t / HID, d = t % HID;
        float a = 0.f;
        #pragma unroll
        for (int n = 0; n < C1; n++) a += sss[n*C2 + c]*x2s[n*HID + d];
        x3s[t] = a;
    }
    {
        float loc = 0.f;
        for (int p = t; p < 1024; p += 256){
            int n = p >> 5, mm = p & 31;
            float dot = 0.f;
            #pragma unroll
            for (int c = 0; c < C2; c++) dot += sss[n*C2 + c]*sss[mm*C2 + c];
            float df = a2s[p] - dot;
            loc += df*df;
        }
        red[t] = loc; __syncthreads();
        for (int s = 128; s > 0; s >>= 1){ if (t < s) red[t] += red[t+s]; __syncthreads(); }
        if (t == 0) atomicAdd(&scal[3], red[0]);
        __syncthreads();
    }
    // ---- phase 4: per-graph MLP from LDS weights ----
    if (t < 32){
        float a = bf1s[t];
        #pragma unroll 8
        for (int k = 0; k < C2*HID; k++) a += x3s[k]*Wf1s[k*32 + t];
        zsh[t] = fmaxf(a, 0.f);
    }
    __syncthreads();
    if (t < 2){
        float a = bf2s[t];
        #pragma unroll
        for (int j = 0; j < 32; j++) a += zsh[j]*Wf2s[j*2 + t];
        out[b*2 + t] = a;
    }
    // ---- phase 5: last finished block assembles the reg scalar ----
    if (t == 0){
        __threadfence();
        unsigned int old = atomicAdd(ctr, 1u);
        if (old == NB - 1){
            float adjsum = atomicAdd(&scal[0], 0.f);
            float tr     = atomicAdd(&scal[1], 0.f);
            float fr     = atomicAdd(&scal[2], 0.f);
            float r2     = atomicAdd(&scal[3], 0.f);
            float reg1 = (adjsum - 2.f*tr + fr) * (1.f/16777216.f);
            float reg2 = r2 * (1.f/16384.f);
            out[32] = 10.f*reg1 + 0.1f*reg2;
        }
    }
}

extern "C" void kernel_launch(void* const* d_in, const int* in_sizes, int n_in,
                              void* d_out, int out_size, void* d_ws, size_t ws_size,
                              hipStream_t stream) {
    const float* x    = (const float*)d_in[0];
    const int*   ei   = (const int*)d_in[1];
    const float* ea   = (const float*)d_in[2];
    // d_in[3] = y (unused); d_in[4] = adj (algebraically eliminated — never read)
    const float* W1   = (const float*)d_in[5];
    const float* as1  = (const float*)d_in[6];
    const float* ad1  = (const float*)d_in[7];
    const float* We1  = (const float*)d_in[8];
    const float* Wp1  = (const float*)d_in[9];
    const float* asp1 = (const float*)d_in[10];
    const float* adp1 = (const float*)d_in[11];
    const float* Wep1 = (const float*)d_in[12];
    const float* Wp2  = (const float*)d_in[13];
    const float* asp2 = (const float*)d_in[14];
    const float* adp2 = (const float*)d_in[15];
    const float* Wep2 = (const float*)d_in[16];
    const float* Wf1  = (const float*)d_in[17];
    const float* bf1  = (const float*)d_in[18];
    const float* Wf2  = (const float*)d_in[19];
    const float* bf2  = (const float*)d_in[20];
    float* out = (float*)d_out;

    const int* srcA = ei;
    const int* dstA = ei + EE;

    char* wp = (char*)d_ws;
    auto carve = [&](size_t bytes)->char*{
        char* p = wp;
        wp += (bytes + 255) & ~(size_t)255;
        return p;
    };
    float* h1    = (float*)carve((size_t)NN*HID*4);
    float* hs1   = (float*)carve((size_t)NN*NHEADS*4);
    float* hd1   = (float*)carve((size_t)NN*NHEADS*4);
    float* lg1T  = (float*)carve((size_t)EE*NHEADS*4);
    float* ewp1s = (float*)carve((size_t)EE*4);
    float* x1    = (float*)carve((size_t)NN*HID*4);
    float* hp1   = (float*)carve((size_t)NN*C1*4);
    float* hsp   = (float*)carve((size_t)NN*4);
    float* hdp   = (float*)carve((size_t)NN*4);
    float* ssoft = (float*)carve((size_t)NN*C1*4);
    // --- zero-init region (contiguous): x2, adj2, Gm — zeroed inside k_hist_chunk ---
    float* x2    = (float*)carve((size_t)NB*C1*HID*4);   // 61440 B (256-aligned)
    float* adj2  = (float*)carve((size_t)NB*C1*C1*4);    // 65536 B
    float* Gm    = (float*)carve((size_t)NB*C1*C1*4);    // 65536 B
    // -------------------------------------------------------------------------------
    float* scal  = (float*)carve(64*4);                  // [0..3] sums, [8] ctr, [16..31] hctr
    unsigned int* ctr  = (unsigned int*)(scal + 8);
    unsigned int* hctr = (unsigned int*)(scal + 16);
    int* histD   = (int*)carve((size_t)NB*CH*NPG*4);     // 1 MB
    int* histS   = (int*)carve((size_t)NB*CH*NPG*4);     // 1 MB
    int* rowptr  = (int*)carve((size_t)(NN+1)*4);
    int* rowptrS = (int*)carve((size_t)(NN+1)*4);
    int* srcs    = (int*)carve((size_t)EE*4);
    int* eid     = (int*)carve((size_t)EE*4);
    int* dsts    = (int*)carve((size_t)EE*4);
    int* nbrS    = (int*)carve((size_t)EE*4);
    int* unbr    = (int*)carve((size_t)EE*4);
    int* ucnt    = (int*)carve((size_t)NN*4);

    hipMemsetAsync(scal, 0, 64*4, stream);   // scal sums + ctr + hctr (only memset left)

    const int TB = 256;

    // merged: hists + inline per-graph cumscan + x2/adj2/Gm zeroing + node projection
    k_hist_chunk<<<dim3(256 + 64), TB, 0, stream>>>(srcA, dstA, histD, histS,
                                                    x, W1, as1, ad1, h1, hs1, hd1,
                                                    rowptr, rowptrS, hctr, x2);
    // deterministic scatter (LDS atomics only)
    k_scatter_det<<<dim3(256), TB, 0, stream>>>(srcA, dstA, rowptr, rowptrS,
                                                histD, histS, srcs, eid, dsts, nbrS);

    // edge proj + conv1 logit planes (coalesced writes)
    k_elogit<<<dim3(2048), TB, 0, stream>>>(ea, We1, Wep1, srcs, eid, dsts, hs1, hd1, lg1T, ewp1s);

    // conv1 agg + pool-conv1 prep + dedup (k_pd folded; dedup blocks first for overlap)
    k_conv1pd<<<dim3(64 + 256), 640, 0, stream>>>(srcs, rowptr, h1, lg1T, x1,
                                                  Wp1, asp1, adp1, hp1, hsp, hdp,
                                                  rowptrS, nbrS, unbr, ucnt, scal);

    // pool-conv1: inline logits + graph-local LDS staging + fused cluster softmax
    k_pool1_agg<<<dim3(256), 512, 0, stream>>>(srcs, rowptr, hp1, hsp, hdp, ewp1s, ssoft);

    // fused T + diffpool partials (k_partials folded into k_T; T buffer eliminated)
    k_Tp<<<dim3(256), 512, 0, stream>>>(rowptrS, unbr, ucnt, ssoft, x1, adj2, Gm, x2);

    // fused tail: finalize + pool-conv2 + diffpool2 + per-graph MLP + reg assembly
    k_tail<<<dim3(NB), TB, 0, stream>>>(x2, adj2, Gm, Wp2, asp2, adp2, Wep2,
                                        Wf1, bf1, Wf2, bf2, out, scal, ctr);
}

// Round 8
// 252.093 us; speedup vs baseline: 1.0499x; 1.0499x over previous
//
#include <hip/hip_runtime.h>
#include <math.h>

#define NB 16
#define NPG 1024
#define DIN 16
#define ED 8
#define NHEADS 5
#define OUT1 6
#define HID 30
#define C1 32
#define C2 4
#define NN (NB*NPG)      // 16384 nodes
#define EE (NN*32)       // 524288 edges
#define EPG 32768        // edges per graph (graph-contiguous in edge_index)
#define CH 16            // chunks per graph
#define CE 2048          // edges per chunk
#define ZTOT (NB*C1*HID + 2*NB*C1*C1)   // 48128 floats: x2+adj2+Gm zero region

__device__ __forceinline__ float lrelu(float v){ return v >= 0.f ? v : 0.2f*v; }

// chunk mapping for 256-block edge kernels: XCD-affine, block -> (g, c)
__device__ __forceinline__ void chunk_gc(int& g, int& c){
    int x = blockIdx.x & 7;
    int j = blockIdx.x >> 3;     // 0..31
    g = x + 8*(j >> 4);          // 2 graphs per XCD
    c = j & 15;
}

// XCD-affinity mapping for 2048-block edge kernels
__device__ __forceinline__ size_t xcd_chunk_base(){
    int x = blockIdx.x & 7;
    int j = blockIdx.x >> 3;            // 0..255 position within this XCD
    int g = x + 8*(j >> 7);             // 2 graphs per XCD
    int c = j & 127;                    // 128 chunks per graph
    return (size_t)g*EPG + (size_t)c*256;
}

// ---------- merged: per-chunk dual LDS histograms (blocks 0..255, also zero x2/adj2/Gm)
//            + node projection (blocks 256..319) ----------
// R7 lesson: the inline cumscan fold regressed (16x256 threads vs 32x1024 -> latency-bound
// scan on the critical path). Cumscan stays a separate kernel; only the 192KB memset is
// folded here (1 coalesced store/thread, consumed by k_Tp 4 dispatches later).
__global__ void k_hist_chunk(const int* __restrict__ src, const int* __restrict__ dst,
                             int* __restrict__ histD, int* __restrict__ histS,
                             const float* __restrict__ x, const float* __restrict__ W1,
                             const float* __restrict__ as1, const float* __restrict__ ad1,
                             float* __restrict__ h1, float* __restrict__ hs1, float* __restrict__ hd1,
                             float* __restrict__ zbase){
    int t = threadIdx.x;
    if (blockIdx.x < 256){
        __shared__ int hD[NPG], hS[NPG];
        // folded zero-init of x2/adj2/Gm (192KB): one store per thread, blocks 0..187
        {
            int i = blockIdx.x*256 + t;
            if (i < ZTOT) zbase[i] = 0.f;
        }
        for (int i = t; i < NPG; i += 256){ hD[i] = 0; hS[i] = 0; }
        __syncthreads();
        int g, c; chunk_gc(g, c);
        size_t e0 = ((size_t)g*CH + c)*CE;
        #pragma unroll
        for (int i = 0; i < 8; i++){
            size_t e = e0 + i*256 + t;
            atomicAdd(&hD[dst[e] & (NPG-1)], 1);
            atomicAdd(&hS[src[e] & (NPG-1)], 1);
        }
        __syncthreads();
        size_t hb = ((size_t)g*CH + c)*NPG;
        for (int i = t; i < NPG; i += 256){
            histD[hb + i] = hD[i];
            histS[hb + i] = hS[i];
        }
        return;
    }
    // node projection part (blocks 256..319)
    __shared__ float Ws[DIN*HID];
    __shared__ float as_s[HID], ad_s[HID];
    for (int i = t; i < DIN*HID; i += blockDim.x) Ws[i] = W1[i];
    if (t < HID){ as_s[t] = as1[t]; ad_s[t] = ad1[t]; }
    __syncthreads();
    int n = (blockIdx.x - 256)*blockDim.x + t;
    if (n >= NN) return;
    float xv[DIN];
    #pragma unroll
    for (int i = 0; i < DIN; i++) xv[i] = x[n*DIN + i];
    float hv[HID];
    #pragma unroll
    for (int j = 0; j < HID; j++){
        float a = 0.f;
        #pragma unroll
        for (int i = 0; i < DIN; i++) a += xv[i]*Ws[i*HID + j];
        hv[j] = a; h1[(size_t)n*HID + j] = a;
    }
    #pragma unroll
    for (int h = 0; h < NHEADS; h++){
        float s = 0.f, d = 0.f;
        #pragma unroll
        for (int c2 = 0; c2 < OUT1; c2++){ s += hv[h*OUT1+c2]*as_s[h*OUT1+c2]; d += hv[h*OUT1+c2]*ad_s[h*OUT1+c2]; }
        hs1[n*NHEADS + h] = s; hd1[n*NHEADS + h] = d;
    }
}

// ---------- fused: per-(g,n) chunk scan (in place) + per-graph node scan -> rowptr ----------
__global__ __launch_bounds__(1024) void k_cumscan(int* __restrict__ histD, int* __restrict__ histS,
                                                  int* __restrict__ rowptr, int* __restrict__ rowptrS){
    __shared__ int wtot[16], wbase[16];
    bool isD = (blockIdx.x < NB);
    int b = isD ? blockIdx.x : (blockIdx.x - NB);
    int* hist = isD ? histD : histS;
    int* rp   = isD ? rowptr : rowptrS;
    int n = threadIdx.x;
    int run = 0;
    #pragma unroll
    for (int c = 0; c < CH; c++){
        size_t idx = ((size_t)b*CH + c)*NPG + n;
        int v = hist[idx];
        hist[idx] = run;
        run += v;
    }
    int lane = n & 63, wv = n >> 6;
    int sincl = run;
    #pragma unroll
    for (int off = 1; off < 64; off <<= 1){
        int v = __shfl_up(sincl, off, 64);
        if (lane >= off) sincl += v;
    }
    if (lane == 63) wtot[wv] = sincl;
    __syncthreads();
    if (n == 0){
        int r = 0;
        #pragma unroll
        for (int w = 0; w < 16; w++){ wbase[w] = r; r += wtot[w]; }
    }
    __syncthreads();
    int excl = wbase[wv] + sincl - run;
    rp[b*NPG + n] = b*EPG + excl;
    if (b == NB-1 && n == NPG-1) rp[NN] = EE;
}

// ---------- deterministic scatter: slot = rowptr + chunk-base + LDS rank (no global atomics) ----------
__global__ void k_scatter_det(const int* __restrict__ src, const int* __restrict__ dst,
                              const int* __restrict__ rowptr, const int* __restrict__ rowptrS,
                              const int* __restrict__ histD, const int* __restrict__ histS,
                              int* __restrict__ srcs, int* __restrict__ eid,
                              int* __restrict__ dsts, int* __restrict__ nbrS){
    __shared__ int baseD[NPG], baseS[NPG];
    int t = threadIdx.x;
    int g, c; chunk_gc(g, c);
    size_t hb = ((size_t)g*CH + c)*NPG;
    for (int i = t; i < NPG; i += 256){
        baseD[i] = rowptr[g*NPG + i] + histD[hb + i];
        baseS[i] = rowptrS[g*NPG + i] + histS[hb + i];
    }
    __syncthreads();
    size_t e0 = ((size_t)g*CH + c)*CE;
    #pragma unroll
    for (int i = 0; i < 8; i++){
        size_t e = e0 + i*256 + t;
        int s = src[e], d = dst[e];
        int p = atomicAdd(&baseD[d & (NPG-1)], 1);
        srcs[p] = s; eid[p] = (int)e; dsts[p] = d;
        int pS = atomicAdd(&baseS[s & (NPG-1)], 1);
        nbrS[pS] = d;
    }
}

// ---------- edge proj + conv1 LOGITS into per-head planes (2048 blocks, coalesced writes) ----------
__global__ void k_elogit(const float* __restrict__ ea, const float* __restrict__ We1,
                         const float* __restrict__ Wep1,
                         const int* __restrict__ srcs, const int* __restrict__ eid,
                         const int* __restrict__ dsts,
                         const float* __restrict__ hs1, const float* __restrict__ hd1,
                         float* __restrict__ lg1T, float* __restrict__ ewp1s){
    __shared__ float W[ED*NHEADS];
    __shared__ float Wp[ED];
    int t = threadIdx.x;
    if (t < ED*NHEADS) W[t] = We1[t];
    if (t < ED) Wp[t] = Wep1[t];
    __syncthreads();
    size_t k = xcd_chunk_base() + t;
    int s = srcs[k], e = eid[k], d = dsts[k];
    float a[ED];
    #pragma unroll
    for (int i = 0; i < ED; i++) a[i] = ea[(size_t)e*ED + i];
    const float* hsr = hs1 + (size_t)s*NHEADS;
    const float* hdr = hd1 + (size_t)d*NHEADS;
    #pragma unroll
    for (int h = 0; h < NHEADS; h++){
        float sv = 0.f;
        #pragma unroll
        for (int i = 0; i < ED; i++) sv += a[i]*W[i*NHEADS + h];
        lg1T[(size_t)h*EE + k] = lrelu(hsr[h] + hdr[h] + sv);
    }
    float sv = 0.f;
    #pragma unroll
    for (int i = 0; i < ED; i++) sv += a[i]*Wp[i];
    ewp1s[k] = sv;
}

// ---------- conv1 aggregation + pool-conv1 prep + dedup (k_pd folded in) ----------
__global__ __launch_bounds__(640) void k_conv1pd(const int* __restrict__ srcs,
                            const int* __restrict__ rowptr,
                            const float* __restrict__ h1, const float* __restrict__ lg1T,
                            float* __restrict__ x1,
                            const float* __restrict__ Wp1, const float* __restrict__ asp,
                            const float* __restrict__ adp,
                            float* __restrict__ hp1, float* __restrict__ hsp,
                            float* __restrict__ hdp,
                            const int* __restrict__ rowptrS, const int* __restrict__ nbrS,
                            int* __restrict__ unbr, int* __restrict__ ucnt,
                            float* __restrict__ scal){
    __shared__ __align__(16) float smem[35968];   // 143872 B (union of both paths)
    int t = threadIdx.x;

    if (blockIdx.x < 64){
        // ---- dedup via per-thread LDS bitmap (256 active threads, 256 nodes/block) ----
        unsigned int* bm = (unsigned int*)smem;          // 256*33
        int* red = (int*)(smem + 256*33);                // 256
        if (t < 256){
            unsigned int* mybm = &bm[t*33];
            #pragma unroll
            for (int i = 0; i < 32; i++) mybm[i] = 0u;
            int n = blockIdx.x*256 + t;
            int cnt = 0;
            int k0 = rowptrS[n], k1 = rowptrS[n+1];
            for (int k = k0; k < k1; k++){
                int m = nbrS[k];
                int loc = m & (NPG-1);
                unsigned int w = (unsigned int)(loc >> 5);
                unsigned int bit = 1u << (loc & 31);
                unsigned int old = mybm[w];
                if (!(old & bit)){
                    mybm[w] = old | bit;
                    unbr[k0 + cnt] = m;
                    cnt++;
                }
            }
            ucnt[n] = cnt;
            red[t] = cnt;
        }
        __syncthreads();
        for (int s = 128; s > 0; s >>= 1){
            if (t < s) red[t] += red[t+s];
            __syncthreads();
        }
        if (t == 0) atomicAdd(&scal[0], (float)red[0]);
        return;
    }

    // ---- conv1 + proj path ----
    float* hls  = smem;            // NPG*HID = 30720 floats (122880 B)
    float* x1s  = smem + 30720;    // 64*33 = 2112 (padded rows)
    float* hp1s = smem + 32832;    // 64*33 = 2112 (padded rows)
    float* Wp1s = smem + 34944;    // 960
    float* as_s = smem + 35904;    // 32
    float* ad_s = smem + 35936;    // 32

    int blk = blockIdx.x - 64;     // 64 is a multiple of 8 -> XCD mapping preserved
    int xx = blk & 7;
    int j = blk >> 3;              // 0..31
    int g = xx + 8*(j >> 4);       // 2 graphs per XCD
    int seg = j & 15;              // 64-node segment
    const float4* hg4 = (const float4*)(h1 + (size_t)g*NPG*HID);
    float4* hls4 = (float4*)hls;
    for (int i = t; i < NPG*HID/4; i += 640) hls4[i] = hg4[i];
    for (int i = t; i < HID*C1; i += 640) Wp1s[i] = Wp1[i];
    if (t < C1){ as_s[t] = asp[t]; ad_s[t] = adp[t]; }
    __syncthreads();

    int nlo = t/10;
    int nl = seg*64 + nlo;
    int r = t - nlo*10;
    int h = r >> 1;
    int q = r & 1;
    int n = g*NPG + nl;
    int k0 = rowptr[n], k1 = rowptr[n+1];
    const float* lgh = lg1T + (size_t)h*EE;
    int off = h*OUT1 + q*3;
    float m = -INFINITY, den = 0.f;
    float acc[3] = {0.f, 0.f, 0.f};
    int k = k0;
    for (; k + 4 <= k1; k += 4){
        float l0 = lgh[k+0], l1 = lgh[k+1], l2 = lgh[k+2], l3 = lgh[k+3];
        int s0 = srcs[k+0] & (NPG-1), s1 = srcs[k+1] & (NPG-1);
        int s2 = srcs[k+2] & (NPG-1), s3 = srcs[k+3] & (NPG-1);
        const float* p0 = hls + s0*HID + off;
        const float* p1 = hls + s1*HID + off;
        const float* p2 = hls + s2*HID + off;
        const float* p3 = hls + s3*HID + off;
        float mb = fmaxf(fmaxf(l0, l1), fmaxf(l2, l3));
        float mn = fmaxf(m, mb);
        float f  = expf(m - mn);       // first batch: exp(-inf)=0
        float e0 = expf(l0 - mn), e1 = expf(l1 - mn);
        float e2 = expf(l2 - mn), e3 = expf(l3 - mn);
        m = mn;
        den = den*f + e0 + e1 + e2 + e3;
        #pragma unroll
        for (int c = 0; c < 3; c++)
            acc[c] = acc[c]*f + e0*p0[c] + e1*p1[c] + e2*p2[c] + e3*p3[c];
    }
    for (; k < k1; k++){
        float l = lgh[k];
        int s = srcs[k] & (NPG-1);
        float mn = fmaxf(m, l);
        float f  = expf(m - mn);
        float ex = expf(l - mn);
        m = mn;
        den = den*f + ex;
        const float* hr = hls + s*HID + off;
        #pragma unroll
        for (int c = 0; c < 3; c++) acc[c] = acc[c]*f + ex*hr[c];
    }
    float inv = 1.f / (den + 1e-16f);
    #pragma unroll
    for (int c = 0; c < 3; c++){
        float v = acc[c]*inv;
        x1[(size_t)n*HID + off + c] = v;
        x1s[nlo*33 + off + c] = v;
    }
    __syncthreads();

    // proj tail: hp1 tile = x1_tile @ Wp1 (identical FMA order to old k_pd)
    int nbase = g*NPG + seg*64;
    for (int o = t; o < 64*C1; o += 640){
        int nn = o >> 5, c = o & 31;
        float a = 0.f;
        #pragma unroll
        for (int d = 0; d < HID; d++) a += x1s[nn*33 + d]*Wp1s[d*C1 + c];
        hp1s[nn*33 + c] = a;
        hp1[(size_t)(nbase + nn)*C1 + c] = a;
    }
    __syncthreads();
    if (t < 64){
        float s = 0.f, dd = 0.f;
        #pragma unroll
        for (int c = 0; c < C1; c++){
            float a = hp1s[t*33 + c];
            s += a*as_s[c]; dd += a*ad_s[c];
        }
        hsp[nbase + t] = s; hdp[nbase + t] = dd;
    }
}

// ---------- pool-conv1 aggregation: graph-local hp1+hsp staged in LDS (float4), inline logits,
//            fused cluster softmax. 256 blocks (16/graph) x 512 threads. ----------
__global__ __launch_bounds__(512) void k_pool1_agg(const int* __restrict__ srcs,
                            const int* __restrict__ rowptr,
                            const float* __restrict__ hp1, const float* __restrict__ hsp,
                            const float* __restrict__ hdp, const float* __restrict__ ewp1s,
                            float* __restrict__ ssoft){
    __shared__ float hls[NPG*33];   // 135168 B, padded rows -> banks rotate
    __shared__ float sm[64*33];     // 8448 B
    __shared__ __align__(16) float hsps[NPG];   // 4096 B
    __shared__ float hdps[64];      // 256 B
    int t = threadIdx.x;
    int xx = blockIdx.x & 7;
    int j = blockIdx.x >> 3;
    int g = xx + 8*(j >> 4);
    int seg = j & 15;
    const float4* hg4 = (const float4*)(hp1 + (size_t)g*NPG*C1);
    for (int i = t; i < NPG*C1/4; i += 512){
        float4 v = hg4[i];
        int s = i >> 3, c = (i & 7)*4;
        float* p = &hls[s*33 + c];
        p[0] = v.x; p[1] = v.y; p[2] = v.z; p[3] = v.w;
    }
    {
        const float4* hs4 = (const float4*)(hsp + (size_t)g*NPG);
        float4* hsps4 = (float4*)hsps;
        for (int i = t; i < NPG/4; i += 512) hsps4[i] = hs4[i];
    }
    if (t < 64) hdps[t] = hdp[g*NPG + seg*64 + t];
    __syncthreads();
    int nl = t >> 3, q = t & 7;
    int n = g*NPG + seg*64 + nl;
    int k0 = rowptr[n], k1 = rowptr[n+1];
    float hdv = hdps[nl];
    float m = -INFINITY, den = 0.f;
    float acc[4] = {0.f, 0.f, 0.f, 0.f};
    int k = k0;
    for (; k + 4 <= k1; k += 4){
        int sl0 = srcs[k+0] & (NPG-1), sl1 = srcs[k+1] & (NPG-1);
        int sl2 = srcs[k+2] & (NPG-1), sl3 = srcs[k+3] & (NPG-1);
        float l0 = lrelu(hsps[sl0] + hdv + ewp1s[k+0]);
        float l1 = lrelu(hsps[sl1] + hdv + ewp1s[k+1]);
        float l2 = lrelu(hsps[sl2] + hdv + ewp1s[k+2]);
        float l3 = lrelu(hsps[sl3] + hdv + ewp1s[k+3]);
        int b0 = sl0*33 + q*4, b1 = sl1*33 + q*4;
        int b2 = sl2*33 + q*4, b3 = sl3*33 + q*4;
        float mb = fmaxf(fmaxf(l0, l1), fmaxf(l2, l3));
        float mn = fmaxf(m, mb);
        float f  = expf(m - mn);
        float e0 = expf(l0 - mn), e1 = expf(l1 - mn);
        float e2 = expf(l2 - mn), e3 = expf(l3 - mn);
        m = mn;
        den = den*f + e0 + e1 + e2 + e3;
        #pragma unroll
        for (int c = 0; c < 4; c++)
            acc[c] = acc[c]*f + e0*hls[b0+c] + e1*hls[b1+c] + e2*hls[b2+c] + e3*hls[b3+c];
    }
    for (; k < k1; k++){
        int sl = srcs[k] & (NPG-1);
        float l = lrelu(hsps[sl] + hdv + ewp1s[k]);
        int b = sl*33 + q*4;
        float mn = fmaxf(m, l);
        float f  = expf(m - mn);
        float ex = expf(l - mn);
        m = mn;
        den = den*f + ex;
        #pragma unroll
        for (int c = 0; c < 4; c++) acc[c] = acc[c]*f + ex*hls[b+c];
    }
    float inv = 1.f / (den + 1e-16f);
    #pragma unroll
    for (int c = 0; c < 4; c++) sm[nl*33 + q*4 + c] = acc[c]*inv;
    __syncthreads();
    // cluster softmax over the node's 32 channels (redundant per slice-thread)
    float mx = -INFINITY;
    #pragma unroll 8
    for (int i = 0; i < C1; i++) mx = fmaxf(mx, sm[nl*33 + i]);
    float sum = 0.f;
    #pragma unroll 8
    for (int i = 0; i < C1; i++) sum += expf(sm[nl*33 + i] - mx);
    float is = 1.f/sum;
    #pragma unroll
    for (int c = 0; c < 4; c++)
        ssoft[(size_t)n*C1 + q*4 + c] = expf(sm[nl*33 + q*4 + c] - mx)*is;
}

// ---------- fused T + diffpool partials (k_partials folded into k_T) ----------
__global__ __launch_bounds__(512) void k_Tp(const int* __restrict__ rowptrS,
                    const int* __restrict__ unbr,
                    const int* __restrict__ ucnt, const float* __restrict__ ssoft,
                    const float* __restrict__ x1,
                    float* __restrict__ adj2, float* __restrict__ Gm,
                    float* __restrict__ x2){
    __shared__ float sls[NPG*33];               // 135168 B
    __shared__ __align__(16) float tsh[64*C1];  // 8192 B
    __shared__ __align__(16) float xsh[64*HID]; // 7680 B
    int t = threadIdx.x;
    int xx = blockIdx.x & 7;
    int j = blockIdx.x >> 3;
    int g = xx + 8*(j >> 4);
    int seg = j & 15;
    const float4* sg4 = (const float4*)(ssoft + (size_t)g*NPG*C1);
    for (int i = t; i < NPG*C1/4; i += 512){
        float4 v = sg4[i];
        int s = i >> 3, c = (i & 7)*4;
        float* p = &sls[s*33 + c];
        p[0] = v.x; p[1] = v.y; p[2] = v.z; p[3] = v.w;
    }
    {
        size_t xbase = ((size_t)g*NPG + seg*64)*HID;
        const float4* x4 = (const float4*)(x1 + xbase);
        float4* xsh4 = (float4*)xsh;
        for (int i = t; i < 64*HID/4; i += 512) xsh4[i] = x4[i];
    }
    __syncthreads();
    int nl = t >> 3, q = t & 7;
    int n = g*NPG + seg*64 + nl;
    int k0 = rowptrS[n];
    int cnt = ucnt[n];
    float acc[4] = {0.f, 0.f, 0.f, 0.f};
    int i = 0;
    for (; i + 4 <= cnt; i += 4){
        int b0 = (unbr[k0+i+0] & (NPG-1))*33 + q*4;
        int b1 = (unbr[k0+i+1] & (NPG-1))*33 + q*4;
        int b2 = (unbr[k0+i+2] & (NPG-1))*33 + q*4;
        int b3 = (unbr[k0+i+3] & (NPG-1))*33 + q*4;
        #pragma unroll
        for (int c = 0; c < 4; c++)
            acc[c] += sls[b0+c] + sls[b1+c] + sls[b2+c] + sls[b3+c];
    }
    for (; i < cnt; i++){
        int b = (unbr[k0+i] & (NPG-1))*33 + q*4;
        #pragma unroll
        for (int c = 0; c < 4; c++) acc[c] += sls[b+c];
    }
    #pragma unroll
    for (int c = 0; c < 4; c++) tsh[nl*C1 + q*4 + c] = acc[c];
    __syncthreads();

    // ---- partials phase (formerly k_partials): 512 threads, 2 outputs each ----
    float accA[2] = {0.f, 0.f}, accG[2] = {0.f, 0.f}, accX[2] = {0.f, 0.f};
    int cA[2], kA[2], cX[2], dX[2];
    #pragma unroll
    for (int q2 = 0; q2 < 2; q2++){
        int p = t + q2*512;
        cA[q2] = p >> 5; kA[q2] = p & 31;
        cX[q2] = p / HID; dX[q2] = p - cX[q2]*HID;   // valid only when p < 960
    }
    const float* srow = sls + (seg*64)*33;
    for (int r = 0; r < 64; r++){
        const float* sr = srow + r*33;
        const float* tr = tsh + r*C1;
        const float* xr = xsh + r*HID;
        #pragma unroll
        for (int q2 = 0; q2 < 2; q2++){
            float sc = sr[cA[q2]];
            accA[q2] += sc*tr[kA[q2]];
            accG[q2] += sc*sr[kA[q2]];
        }
        #pragma unroll
        for (int q2 = 0; q2 < 2; q2++){
            int p = t + q2*512;
            if (p < C1*HID) accX[q2] += sr[cX[q2]]*xr[dX[q2]];
        }
    }
    int b = g;
    #pragma unroll
    for (int q2 = 0; q2 < 2; q2++){
        int p = t + q2*512;
        atomicAdd(&adj2[(size_t)b*1024 + p], accA[q2]);
        atomicAdd(&Gm[(size_t)b*1024 + p], accG[q2]);
        if (p < C1*HID) atomicAdd(&x2[((size_t)b*C1 + cX[q2])*HID + dX[q2]], accX[q2]);
    }
}

// ---------- fused tail: all weights LDS-staged in one burst ----------
__global__ __launch_bounds__(256) void k_tail(const float* __restrict__ x2, const float* __restrict__ adj2,
                       const float* __restrict__ Gm,
                       const float* __restrict__ Wp2, const float* __restrict__ asp,
                       const float* __restrict__ adp, const float* __restrict__ Wep2,
                       const float* __restrict__ Wf1, const float* __restrict__ bf1,
                       const float* __restrict__ Wf2, const float* __restrict__ bf2,
                       float* __restrict__ out, float* __restrict__ scal,
                       unsigned int* __restrict__ ctr){
    int b = blockIdx.x;
    int t = threadIdx.x;  // 256
    __shared__ float x2s[C1*HID];     // 960
    __shared__ float a2s[C1*C1];      // 1024
    __shared__ float Wps[HID*C2];     // 120
    __shared__ float Wf1s[C2*HID*32]; // 3840 (15360 B)
    __shared__ float asps[C2], adps[C2];
    __shared__ float bf1s[32], Wf2s[64], bf2s[2];
    __shared__ float wepsh;
    __shared__ float h2s[C1*C2];
    __shared__ float hs2s[C1], hd2s[C1];
    __shared__ float sss[C1*C2];      // softmax(s2)
    __shared__ float x3s[C2*HID];     // 120
    __shared__ float zsh[32];
    __shared__ float red[256], red2[256];

    // ---- one batched, coalesced load burst: everything this kernel will ever read ----
    float gv[4];
    #pragma unroll
    for (int q = 0; q < 4; q++) gv[q] = Gm[(size_t)b*1024 + t + q*256];
    for (int i = t; i < C1*HID; i += 256) x2s[i] = x2[(size_t)b*C1*HID + i];
    for (int i = t; i < C1*C1; i += 256) a2s[i] = adj2[(size_t)b*C1*C1 + i];
    for (int i = t; i < C2*HID*32; i += 256) Wf1s[i] = Wf1[i];
    if (t < HID*C2) Wps[t] = Wp2[t];
    if (t < C2){ asps[t] = asp[t]; adps[t] = adp[t]; }
    if (t < 32) bf1s[t] = bf1[t];
    if (t < 64) Wf2s[t] = Wf2[t];
    if (t < 2)  bf2s[t] = bf2[t];
    if (t == 0) wepsh = Wep2[0];
    __syncthreads();

    // ---- phase 1a (parallel over 128 threads): h2 = x2@Wp2 ----
    if (t < C1*C2){
        int i = t >> 2, c = t & 3;
        float a = 0.f;
        #pragma unroll
        for (int d = 0; d < HID; d++) a += x2s[i*HID + d]*Wps[d*C2 + c];
        h2s[t] = a;
    }
    // ---- fused reductions: trace(adj2) + ||G||_F^2 (one tree, two lanes) ----
    {
        float lfr = gv[0]*gv[0] + gv[1]*gv[1] + gv[2]*gv[2] + gv[3]*gv[3];
        float ltr = (t < C1) ? a2s[t*33] : 0.f;   // diag: t*C1+t
        red[t] = ltr; red2[t] = lfr;
        __syncthreads();
        for (int s = 128; s > 0; s >>= 1){
            if (t < s){ red[t] += red[t+s]; red2[t] += red2[t+s]; }
            __syncthreads();
        }
        if (t == 0){ atomicAdd(&scal[1], red[0]); atomicAdd(&scal[2], red2[0]); }
    }
    // ---- phase 1b: attention scalars ----
    if (t < C1){
        float s = 0.f, dd = 0.f;
        #pragma unroll
        for (int c = 0; c < C2; c++){ s += h2s[t*C2 + c]*asps[c]; dd += h2s[t*C2 + c]*adps[c]; }
        hs2s[t] = s; hd2s[t] = dd;
    }
    __syncthreads();
    // ---- phase 2: dense EGAT agg over 32 sources + softmax over C2 (all LDS) ----
    if (t < C1){
        int j = t;
        float hdv = hd2s[j];
        float wep = wepsh;
        float m = -INFINITY;
        for (int i = 0; i < C1; i++)
            m = fmaxf(m, lrelu(hs2s[i] + hdv + a2s[i*C1 + j]*wep));
        float den = 0.f;
        float acc[C2] = {0,0,0,0};
        for (int i = 0; i < C1; i++){
            float ex = expf(lrelu(hs2s[i] + hdv + a2s[i*C1 + j]*wep) - m);
            den += ex;
            #pragma unroll
            for (int c = 0; c < C2; c++) acc[c] += ex * h2s[i*C2 + c];
        }
        float inv = 1.f/(den + 1e-16f);
        float v[C2]; float mx = -INFINITY;
        #pragma unroll
        for (int c = 0; c < C2; c++){ v[c] = acc[c]*inv; mx = fmaxf(mx, v[c]); }
        float sum = 0.f;
        #pragma unroll
        for (int c = 0; c < C2; c++){ v[c] = expf(v[c] - mx); sum += v[c]; }
        float i2 = 1.f/sum;
        #pragma unroll
        for (int c = 0; c < C2; c++) sss[j*C2 + c] = v[c]*i2;
    }
    __syncthreads();
    // ---- phase 3: x3 = S^T x2 (LDS only) and reg2 ----
    if (t < C2*HID){
        int c = t / HID, d = t % HID;
        float a = 0.f;
        #pragma unroll
        for (int n = 0; n < C1; n++) a += sss[n*C2 + c]*x2s[n*HID + d];
        x3s[t] = a;
    }
    {
        float loc = 0.f;
        for (int p = t; p < 1024; p += 256){
            int n = p >> 5, mm = p & 31;
            float dot = 0.f;
            #pragma unroll
            for (int c = 0; c < C2; c++) dot += sss[n*C2 + c]*sss[mm*C2 + c];
            float df = a2s[p] - dot;
            loc += df*df;
        }
        red[t] = loc; __syncthreads();
        for (int s = 128; s > 0; s >>= 1){ if (t < s) red[t] += red[t+s]; __syncthreads(); }
        if (t == 0) atomicAdd(&scal[3], red[0]);
        __syncthreads();
    }
    // ---- phase 4: per-graph MLP from LDS weights ----
    if (t < 32){
        float a = bf1s[t];
        #pragma unroll 8
        for (int k = 0; k < C2*HID; k++) a += x3s[k]*Wf1s[k*32 + t];
        zsh[t] = fmaxf(a, 0.f);
    }
    __syncthreads();
    if (t < 2){
        float a = bf2s[t];
        #pragma unroll
        for (int j = 0; j < 32; j++) a += zsh[j]*Wf2s[j*2 + t];
        out[b*2 + t] = a;
    }
    // ---- phase 5: last finished block assembles the reg scalar ----
    if (t == 0){
        __threadfence();
        unsigned int old = atomicAdd(ctr, 1u);
        if (old == NB - 1){
            float adjsum = atomicAdd(&scal[0], 0.f);
            float tr     = atomicAdd(&scal[1], 0.f);
            float fr     = atomicAdd(&scal[2], 0.f);
            float r2     = atomicAdd(&scal[3], 0.f);
            float reg1 = (adjsum - 2.f*tr + fr) * (1.f/16777216.f);
            float reg2 = r2 * (1.f/16384.f);
            out[32] = 10.f*reg1 + 0.1f*reg2;
        }
    }
}

extern "C" void kernel_launch(void* const* d_in, const int* in_sizes, int n_in,
                              void* d_out, int out_size, void* d_ws, size_t ws_size,
                              hipStream_t stream) {
    const float* x    = (const float*)d_in[0];
    const int*   ei   = (const int*)d_in[1];
    const float* ea   = (const float*)d_in[2];
    // d_in[3] = y (unused); d_in[4] = adj (algebraically eliminated — never read)
    const float* W1   = (const float*)d_in[5];
    const float* as1  = (const float*)d_in[6];
    const float* ad1  = (const float*)d_in[7];
    const float* We1  = (const float*)d_in[8];
    const float* Wp1  = (const float*)d_in[9];
    const float* asp1 = (const float*)d_in[10];
    const float* adp1 = (const float*)d_in[11];
    const float* Wep1 = (const float*)d_in[12];
    const float* Wp2  = (const float*)d_in[13];
    const float* asp2 = (const float*)d_in[14];
    const float* adp2 = (const float*)d_in[15];
    const float* Wep2 = (const float*)d_in[16];
    const float* Wf1  = (const float*)d_in[17];
    const float* bf1  = (const float*)d_in[18];
    const float* Wf2  = (const float*)d_in[19];
    const float* bf2  = (const float*)d_in[20];
    float* out = (float*)d_out;

    const int* srcA = ei;
    const int* dstA = ei + EE;

    char* wp = (char*)d_ws;
    auto carve = [&](size_t bytes)->char*{
        char* p = wp;
        wp += (bytes + 255) & ~(size_t)255;
        return p;
    };
    float* h1    = (float*)carve((size_t)NN*HID*4);
    float* hs1   = (float*)carve((size_t)NN*NHEADS*4);
    float* hd1   = (float*)carve((size_t)NN*NHEADS*4);
    float* lg1T  = (float*)carve((size_t)EE*NHEADS*4);
    float* ewp1s = (float*)carve((size_t)EE*4);
    float* x1    = (float*)carve((size_t)NN*HID*4);
    float* hp1   = (float*)carve((size_t)NN*C1*4);
    float* hsp   = (float*)carve((size_t)NN*4);
    float* hdp   = (float*)carve((size_t)NN*4);
    float* ssoft = (float*)carve((size_t)NN*C1*4);
    // --- zero-init region (contiguous): x2, adj2, Gm — zeroed inside k_hist_chunk ---
    float* x2    = (float*)carve((size_t)NB*C1*HID*4);   // 61440 B (256-aligned)
    float* adj2  = (float*)carve((size_t)NB*C1*C1*4);    // 65536 B
    float* Gm    = (float*)carve((size_t)NB*C1*C1*4);    // 65536 B
    // -------------------------------------------------------------------------------
    float* scal  = (float*)carve(16*4);                  // [0..3] sums, [8] ctr
    unsigned int* ctr = (unsigned int*)(scal + 8);
    int* histD   = (int*)carve((size_t)NB*CH*NPG*4);     // 1 MB
    int* histS   = (int*)carve((size_t)NB*CH*NPG*4);     // 1 MB
    int* rowptr  = (int*)carve((size_t)(NN+1)*4);
    int* rowptrS = (int*)carve((size_t)(NN+1)*4);
    int* srcs    = (int*)carve((size_t)EE*4);
    int* eid     = (int*)carve((size_t)EE*4);
    int* dsts    = (int*)carve((size_t)EE*4);
    int* nbrS    = (int*)carve((size_t)EE*4);
    int* unbr    = (int*)carve((size_t)EE*4);
    int* ucnt    = (int*)carve((size_t)NN*4);

    hipMemsetAsync(scal, 0, 16*4, stream);   // only scal/ctr memset remains

    const int TB = 256;

    // merged: per-chunk dual LDS histograms + x2/adj2/Gm zeroing + node projection
    k_hist_chunk<<<dim3(256 + 64), TB, 0, stream>>>(srcA, dstA, histD, histS,
                                                    x, W1, as1, ad1, h1, hs1, hd1, x2);
    // fused chunk-scan + per-graph node scan -> rowptr/rowptrS (32x1024: full parallelism)
    k_cumscan<<<dim3(2*NB), 1024, 0, stream>>>(histD, histS, rowptr, rowptrS);
    // deterministic scatter (LDS atomics only)
    k_scatter_det<<<dim3(256), TB, 0, stream>>>(srcA, dstA, rowptr, rowptrS,
                                                histD, histS, srcs, eid, dsts, nbrS);

    // edge proj + conv1 logit planes (coalesced writes)
    k_elogit<<<dim3(2048), TB, 0, stream>>>(ea, We1, Wep1, srcs, eid, dsts, hs1, hd1, lg1T, ewp1s);

    // conv1 agg + pool-conv1 prep + dedup (k_pd folded; dedup blocks first for overlap)
    k_conv1pd<<<dim3(64 + 256), 640, 0, stream>>>(srcs, rowptr, h1, lg1T, x1,
                                                  Wp1, asp1, adp1, hp1, hsp, hdp,
                                                  rowptrS, nbrS, unbr, ucnt, scal);

    // pool-conv1: inline logits + graph-local LDS staging + fused cluster softmax
    k_pool1_agg<<<dim3(256), 512, 0, stream>>>(srcs, rowptr, hp1, hsp, hdp, ewp1s, ssoft);

    // fused T + diffpool partials (k_partials folded into k_T; T buffer eliminated)
    k_Tp<<<dim3(256), 512, 0, stream>>>(rowptrS, unbr, ucnt, ssoft, x1, adj2, Gm, x2);

    // fused tail: finalize + pool-conv2 + diffpool2 + per-graph MLP + reg assembly
    k_tail<<<dim3(NB), TB, 0, stream>>>(x2, adj2, Gm, Wp2, asp2, adp2, Wep2,
                                        Wf1, bf1, Wf2, bf2, out, scal, ctr);
}